// Round 3
// baseline (4805.424 us; speedup 1.0000x reference)
//
#include <hip/hip_runtime.h>
#include <math.h>

#define B_ 128
#define P_ 196
#define E_ 2048
#define D_ 512
#define A_ 512
#define M_ 512
#define V_ 10000
#define L_ 21
#define T_ 20

typedef __attribute__((ext_vector_type(8))) short bf16x8;
typedef __attribute__((ext_vector_type(4))) float f32x4;

// ---------------------------------------------------------------------------
// order kernel: stable argsort by descending caption length (B=128)
// ---------------------------------------------------------------------------
__global__ void order_kernel(const int* __restrict__ lens, const int* __restrict__ caps,
                             int* __restrict__ order, int* __restrict__ declen,
                             int* __restrict__ row_map, int* __restrict__ tok_rows) {
  __shared__ int s_order[B_];
  int tid = threadIdx.x;
  if (tid < B_) {
    int li = lens[tid];
    int r = 0;
    for (int j = 0; j < B_; ++j) {
      int lj = lens[j];
      r += (lj > li) || (lj == li && j < tid);
    }
    s_order[r] = tid;
    declen[r] = li - 1;
  }
  __syncthreads();
  if (tid < B_) order[tid] = s_order[tid];
  for (int m = tid; m < B_ * P_; m += blockDim.x) {
    int b = m / P_, p = m - b * P_;
    row_map[m] = s_order[b] * P_ + p;
  }
  for (int i = tid; i < T_ * B_; i += blockDim.x) {
    int t = i >> 7, b = i & 127;
    tok_rows[i] = caps[s_order[b] * L_ + t];
  }
}

// ---------------------------------------------------------------------------
// mean over P of sorted encoder rows
// ---------------------------------------------------------------------------
__global__ void mean_kernel(const float* __restrict__ enc, const int* __restrict__ order,
                            float* __restrict__ mean) {
  int b = blockIdx.y;
  int e = blockIdx.x * blockDim.x + threadIdx.x;
  int ob = order[b];
  const float* base = enc + (long long)ob * P_ * E_ + e;
  float s = 0.f;
  for (int p = 0; p < P_; ++p) s += base[(long long)p * E_];
  mean[b * E_ + e] = s * (1.0f / P_);
}

// ---------------------------------------------------------------------------
// 32x32 fp32 transpose: out[n*2048+k] = in[k*512+n]   (enc_att_w -> [512][2048])
// grid (16, 64), 256 threads
// ---------------------------------------------------------------------------
__global__ void transpose_kernel(const float* __restrict__ in, float* __restrict__ out) {
  __shared__ float t[32][33];
  int bx = blockIdx.x * 32;  // n
  int by = blockIdx.y * 32;  // k
  int lx = threadIdx.x & 31, ly = threadIdx.x >> 5;  // ly 0..7
#pragma unroll
  for (int i = 0; i < 32; i += 8) t[ly + i][lx] = in[(by + ly + i) * 512 + bx + lx];
  __syncthreads();
#pragma unroll
  for (int i = 0; i < 32; i += 8) out[(long long)(bx + ly + i) * 2048 + by + lx] = t[lx][ly + i];
}

// ---------------------------------------------------------------------------
// fp32 tiled GEMM (kept for h0/c0 init): C = A@B + bias, B row-major [K,N]
// ---------------------------------------------------------------------------
__global__ __launch_bounds__(256) void gemm32_kernel(
    const float* __restrict__ A, const float* __restrict__ Bm,
    const float* __restrict__ bias, float* __restrict__ C,
    int M, int N, int K, float* __restrict__ xh_dup) {
  __shared__ float As[16][64];
  __shared__ float Bs[16][64];
  const int tid = threadIdx.x;
  const int bm = blockIdx.y * 64, bn = blockIdx.x * 64;
  const int tm = tid >> 4, tn = tid & 15;
  float acc[4][4];
#pragma unroll
  for (int i = 0; i < 4; ++i)
#pragma unroll
    for (int j = 0; j < 4; ++j) acc[i][j] = 0.f;
  const int lm = tid >> 2;
  const int lk = (tid & 3) * 4;
  for (int k0 = 0; k0 < K; k0 += 16) {
    {
      int m = bm + lm;
      float4 v = make_float4(0.f, 0.f, 0.f, 0.f);
      if (m < M) v = *(const float4*)(A + (long long)m * K + k0 + lk);
      As[lk + 0][lm] = v.x;
      As[lk + 1][lm] = v.y;
      As[lk + 2][lm] = v.z;
      As[lk + 3][lm] = v.w;
    }
    {
      int k = tid >> 4;
      int n4 = (tid & 15) * 4;
      int n = bn + n4;
      float4 v = make_float4(0.f, 0.f, 0.f, 0.f);
      if (n < N) v = *(const float4*)(Bm + (long long)(k0 + k) * N + n);
      Bs[k][n4 + 0] = v.x;
      Bs[k][n4 + 1] = v.y;
      Bs[k][n4 + 2] = v.z;
      Bs[k][n4 + 3] = v.w;
    }
    __syncthreads();
#pragma unroll
    for (int k = 0; k < 16; ++k) {
      float a0 = As[k][tm * 4 + 0], a1 = As[k][tm * 4 + 1];
      float a2 = As[k][tm * 4 + 2], a3 = As[k][tm * 4 + 3];
      float b0 = Bs[k][tn * 4 + 0], b1 = Bs[k][tn * 4 + 1];
      float b2 = Bs[k][tn * 4 + 2], b3 = Bs[k][tn * 4 + 3];
      acc[0][0] += a0 * b0; acc[0][1] += a0 * b1; acc[0][2] += a0 * b2; acc[0][3] += a0 * b3;
      acc[1][0] += a1 * b0; acc[1][1] += a1 * b1; acc[1][2] += a1 * b2; acc[1][3] += a1 * b3;
      acc[2][0] += a2 * b0; acc[2][1] += a2 * b1; acc[2][2] += a2 * b2; acc[2][3] += a2 * b3;
      acc[3][0] += a3 * b0; acc[3][1] += a3 * b1; acc[3][2] += a3 * b2; acc[3][3] += a3 * b3;
    }
    __syncthreads();
  }
#pragma unroll
  for (int i = 0; i < 4; ++i) {
    int m = bm + tm * 4 + i;
    if (m >= M) continue;
#pragma unroll
    for (int j = 0; j < 4; ++j) {
      int n = bn + tn * 4 + j;
      if (n >= N) continue;
      float v = acc[i][j] + (bias ? bias[n] : 0.f);
      C[(long long)m * N + n] = v;
      if (xh_dup) xh_dup[m * 2560 + 2048 + n] = v;
    }
  }
}

// ---------------------------------------------------------------------------
// bf16(+split) MFMA GEMM.  A fp32 [M,K]-ish (lda, optional row_map);
// B fp32 [N,K] row-major (ldb).  On-the-fly fp32 -> bf16 hi/lo staging.
// 128x128 tile, BK=32, 4 waves, 16x16x32 MFMA.
// MODE 0: C[m*ldc+n] = acc + bias[n] (+bias2[n])
// MODE 1: fc scatter: b=m&127, t=m>>7, masked by declen
// MODE 2: gemm2 split-K chunks via blockIdx.z (A=xh, B=w_ih/w_hh)
// ---------------------------------------------------------------------------
__device__ __forceinline__ unsigned f2bf_u(float f) {
  unsigned u = __float_as_uint(f);
  return (u + 0x7fffu + ((u >> 16) & 1u)) >> 16;
}

__device__ __forceinline__ void stage16(short* __restrict__ Ph, short* __restrict__ Pl,
                                        int r, int kq, float4 v0, float4 v1, float4 v2,
                                        float4 v3, bool split) {
  float f[16] = {v0.x, v0.y, v0.z, v0.w, v1.x, v1.y, v1.z, v1.w,
                 v2.x, v2.y, v2.z, v2.w, v3.x, v3.y, v3.z, v3.w};
#pragma unroll
  for (int g2 = 0; g2 < 2; ++g2) {
    int gg = (kq >> 3) + g2;
    int slot = gg ^ ((r >> 1) & 3);
    unsigned hb[8];
    float lf[8];
#pragma unroll
    for (int j = 0; j < 8; ++j) {
      float x = f[g2 * 8 + j];
      hb[j] = f2bf_u(x);
      lf[j] = x - __uint_as_float(hb[j] << 16);
    }
    int4 ph;
    ph.x = (int)(hb[0] | (hb[1] << 16));
    ph.y = (int)(hb[2] | (hb[3] << 16));
    ph.z = (int)(hb[4] | (hb[5] << 16));
    ph.w = (int)(hb[6] | (hb[7] << 16));
    *(int4*)&Ph[r * 32 + slot * 8] = ph;
    if (split) {
      unsigned lb[8];
#pragma unroll
      for (int j = 0; j < 8; ++j) lb[j] = f2bf_u(lf[j]);
      int4 pl;
      pl.x = (int)(lb[0] | (lb[1] << 16));
      pl.y = (int)(lb[2] | (lb[3] << 16));
      pl.z = (int)(lb[4] | (lb[5] << 16));
      pl.w = (int)(lb[6] | (lb[7] << 16));
      *(int4*)&Pl[r * 32 + slot * 8] = pl;
    }
  }
}

__device__ __forceinline__ bf16x8 frag_load(const short* __restrict__ P, int row, int g) {
  int slot = g ^ ((row >> 1) & 3);
  return *(const bf16x8*)&P[row * 32 + slot * 8];
}

template <int MODE, bool SPLIT>
__global__ __launch_bounds__(256) void mfma_gemm(
    const float* __restrict__ A, int lda, const int* __restrict__ row_map,
    const float* __restrict__ Bn, int ldb,
    const float* __restrict__ bias, const float* __restrict__ bias2,
    float* __restrict__ C, int ldc, int M, int N, int K,
    const float* __restrict__ whh, const int* __restrict__ declen) {
  __shared__ short Ah[128 * 32];
  __shared__ short Bh[128 * 32];
  __shared__ short Al[128 * 32];
  __shared__ short Bl[128 * 32];
  const int tid = threadIdx.x;
  int bm = blockIdx.y * 128, bn = blockIdx.x * 128;
  if (MODE == 2) {
    int z = blockIdx.z;
    A += z * 512;  // xh chunk, lda = 2560
    if (z < 4) {
      Bn += 512 + z * 512;  // w_ih cols (512 + z*512 ..), ldb = 2560
    } else {
      Bn = whh;
      ldb = 512;
    }
    C += (long long)z * (128 * 2048);
  }
  f32x4 acc[4][4];
#pragma unroll
  for (int i = 0; i < 4; ++i)
#pragma unroll
    for (int j = 0; j < 4; ++j) acc[i][j] = (f32x4){0.f, 0.f, 0.f, 0.f};

  const int r = tid >> 1;
  const int kq = (tid & 1) * 16;
  const int am = bm + r;
  const long long arow = row_map ? (long long)row_map[am] : (long long)am;
  const float* ap = A + arow * (long long)lda + kq;
  const int gn = bn + r;
  const float* bp = Bn + (long long)gn * ldb + kq;
  const bool bok = gn < N;

  const int lane = tid & 63;
  const int wv = tid >> 6, wr = wv >> 1, wc = wv & 1;
  const int lr = lane & 15, g = lane >> 4;

  for (int k0 = 0; k0 < K; k0 += 32) {
    float4 a0 = *(const float4*)(ap + k0);
    float4 a1 = *(const float4*)(ap + k0 + 4);
    float4 a2 = *(const float4*)(ap + k0 + 8);
    float4 a3 = *(const float4*)(ap + k0 + 12);
    float4 z4 = make_float4(0.f, 0.f, 0.f, 0.f);
    float4 b0 = bok ? *(const float4*)(bp + k0) : z4;
    float4 b1 = bok ? *(const float4*)(bp + k0 + 4) : z4;
    float4 b2 = bok ? *(const float4*)(bp + k0 + 8) : z4;
    float4 b3 = bok ? *(const float4*)(bp + k0 + 12) : z4;
    stage16(Ah, Al, r, kq, a0, a1, a2, a3, SPLIT);
    stage16(Bh, Bl, r, kq, b0, b1, b2, b3, SPLIT);
    __syncthreads();
    bf16x8 ah[4], bh[4];
#pragma unroll
    for (int i = 0; i < 4; ++i) {
      ah[i] = frag_load(Ah, wr * 64 + i * 16 + lr, g);
      bh[i] = frag_load(Bh, wc * 64 + i * 16 + lr, g);
    }
#pragma unroll
    for (int i = 0; i < 4; ++i)
#pragma unroll
      for (int j = 0; j < 4; ++j)
        acc[i][j] = __builtin_amdgcn_mfma_f32_16x16x32_bf16(ah[i], bh[j], acc[i][j], 0, 0, 0);
    if (SPLIT) {
      bf16x8 al2[4], bl2[4];
#pragma unroll
      for (int i = 0; i < 4; ++i) {
        al2[i] = frag_load(Al, wr * 64 + i * 16 + lr, g);
        bl2[i] = frag_load(Bl, wc * 64 + i * 16 + lr, g);
      }
#pragma unroll
      for (int i = 0; i < 4; ++i)
#pragma unroll
        for (int j = 0; j < 4; ++j)
          acc[i][j] = __builtin_amdgcn_mfma_f32_16x16x32_bf16(al2[i], bh[j], acc[i][j], 0, 0, 0);
#pragma unroll
      for (int i = 0; i < 4; ++i)
#pragma unroll
        for (int j = 0; j < 4; ++j)
          acc[i][j] = __builtin_amdgcn_mfma_f32_16x16x32_bf16(ah[i], bl2[j], acc[i][j], 0, 0, 0);
    }
    __syncthreads();
  }

#pragma unroll
  for (int j = 0; j < 4; ++j) {
    int n = bn + wc * 64 + j * 16 + lr;
    float bj = 0.f;
    if (n < N) {
      if (bias) bj += bias[n];
      if (bias2) bj += bias2[n];
    }
#pragma unroll
    for (int i = 0; i < 4; ++i) {
#pragma unroll
      for (int rr = 0; rr < 4; ++rr) {
        int m = bm + wr * 64 + i * 16 + g * 4 + rr;
        float v = acc[i][j][rr] + bj;
        if (MODE == 0) {
          C[(long long)m * ldc + n] = v;
        } else if (MODE == 1) {
          if (n < N) {
            int b = m & 127, t = m >> 7;
            C[(long long)b * (T_ * V_) + (long long)t * V_ + n] = (t < declen[b]) ? v : 0.f;
          }
        } else {
          C[(long long)m * ldc + n] = v;
        }
      }
    }
  }
}

// ---------------------------------------------------------------------------
// step1: fused att2 + f_beta-gate GEMM (fp32, small)
// ---------------------------------------------------------------------------
__global__ __launch_bounds__(256) void step1_kernel(
    const float* __restrict__ h, const float* __restrict__ dec_att_w,
    const float* __restrict__ dec_att_b, const float* __restrict__ f_beta_w,
    const float* __restrict__ f_beta_b, float* __restrict__ att2,
    float* __restrict__ gate) {
  __shared__ float As[16][64];
  __shared__ float Bs[16][64];
  const int tid = threadIdx.x;
  const int bm = blockIdx.y * 64, bn = blockIdx.x * 64;
  const bool isatt = bn < 512;
  const float* Bp = isatt ? dec_att_w : f_beta_w;
  const int bstride = isatt ? 512 : 2048;
  const int ncol0 = isatt ? bn : bn - 512;
  const int tm = tid >> 4, tn = tid & 15;
  float acc[4][4];
#pragma unroll
  for (int i = 0; i < 4; ++i)
#pragma unroll
    for (int j = 0; j < 4; ++j) acc[i][j] = 0.f;
  const int lm = tid >> 2;
  const int lk = (tid & 3) * 4;
  for (int k0 = 0; k0 < 512; k0 += 16) {
    {
      int m = bm + lm;
      float4 v = *(const float4*)(h + m * 512 + k0 + lk);
      As[lk + 0][lm] = v.x;
      As[lk + 1][lm] = v.y;
      As[lk + 2][lm] = v.z;
      As[lk + 3][lm] = v.w;
    }
    {
      int k = tid >> 4;
      int n4 = (tid & 15) * 4;
      float4 v = *(const float4*)(Bp + (k0 + k) * bstride + ncol0 + n4);
      Bs[k][n4 + 0] = v.x;
      Bs[k][n4 + 1] = v.y;
      Bs[k][n4 + 2] = v.z;
      Bs[k][n4 + 3] = v.w;
    }
    __syncthreads();
#pragma unroll
    for (int k = 0; k < 16; ++k) {
      float a0 = As[k][tm * 4 + 0], a1 = As[k][tm * 4 + 1];
      float a2 = As[k][tm * 4 + 2], a3 = As[k][tm * 4 + 3];
      float b0 = Bs[k][tn * 4 + 0], b1 = Bs[k][tn * 4 + 1];
      float b2 = Bs[k][tn * 4 + 2], b3 = Bs[k][tn * 4 + 3];
      acc[0][0] += a0 * b0; acc[0][1] += a0 * b1; acc[0][2] += a0 * b2; acc[0][3] += a0 * b3;
      acc[1][0] += a1 * b0; acc[1][1] += a1 * b1; acc[1][2] += a1 * b2; acc[1][3] += a1 * b3;
      acc[2][0] += a2 * b0; acc[2][1] += a2 * b1; acc[2][2] += a2 * b2; acc[2][3] += a2 * b3;
      acc[3][0] += a3 * b0; acc[3][1] += a3 * b1; acc[3][2] += a3 * b2; acc[3][3] += a3 * b3;
    }
    __syncthreads();
  }
#pragma unroll
  for (int i = 0; i < 4; ++i) {
    int m = bm + tm * 4 + i;
#pragma unroll
    for (int j = 0; j < 4; ++j) {
      int nc = ncol0 + tn * 4 + j;
      float v = acc[i][j];
      if (isatt) {
        att2[m * 512 + nc] = v + dec_att_b[nc];
      } else {
        v += f_beta_b[nc];
        gate[m * 2048 + nc] = 1.f / (1.f + __expf(-v));
      }
    }
  }
}

// ---------------------------------------------------------------------------
// e + softmax + alpha
// ---------------------------------------------------------------------------
__global__ __launch_bounds__(256) void esm_kernel(
    const float* __restrict__ att1, const float* __restrict__ att2,
    const float* __restrict__ w, const float* __restrict__ fb,
    const int* __restrict__ declen, int t,
    float* __restrict__ alpha_ws, float* __restrict__ alpha_out) {
  __shared__ float att2_s[A_];
  __shared__ float w_s[A_];
  __shared__ float e_s[P_];
  __shared__ float red[8];
  int b = blockIdx.x, tid = threadIdx.x;
  for (int i = tid; i < A_; i += 256) {
    att2_s[i] = att2[b * A_ + i];
    w_s[i] = w[i];
  }
  __syncthreads();
  int wave = tid >> 6, lane = tid & 63;
  for (int p = wave; p < P_; p += 4) {
    const float* row = att1 + ((long long)b * P_ + p) * A_;
    float s = 0.f;
#pragma unroll
    for (int i = 0; i < A_ / 64; ++i) {
      int idx = lane + i * 64;
      float v = row[idx] + att2_s[idx];
      s += (v > 0.f ? v : 0.f) * w_s[idx];
    }
    for (int off = 32; off; off >>= 1) s += __shfl_down(s, off);
    if (lane == 0) e_s[p] = s + fb[0];
  }
  __syncthreads();
  float m = -1e30f;
  for (int p = tid; p < P_; p += 256) m = fmaxf(m, e_s[p]);
  for (int off = 32; off; off >>= 1) m = fmaxf(m, __shfl_down(m, off));
  if (lane == 0) red[wave] = m;
  __syncthreads();
  m = fmaxf(fmaxf(red[0], red[1]), fmaxf(red[2], red[3]));
  float ssum = 0.f;
  for (int p = tid; p < P_; p += 256) {
    float ev = __expf(e_s[p] - m);
    e_s[p] = ev;
    ssum += ev;
  }
  for (int off = 32; off; off >>= 1) ssum += __shfl_down(ssum, off);
  if (lane == 0) red[4 + wave] = ssum;
  __syncthreads();
  ssum = red[4] + red[5] + red[6] + red[7];
  float inv = 1.f / ssum;
  bool active = (t < declen[b]);
  for (int p = tid; p < P_; p += 256) {
    float al = e_s[p] * inv;
    alpha_ws[b * P_ + p] = al;
    alpha_out[(long long)b * (T_ * P_) + t * P_ + p] = active ? al : 0.f;
  }
}

// ---------------------------------------------------------------------------
// awe: xh[b, e] = gate[b,e] * sum_p alpha[b,p] * enc[ob,p,e]
// ---------------------------------------------------------------------------
__global__ __launch_bounds__(256) void awe_kernel(
    const float* __restrict__ alpha_ws, const float* __restrict__ enc,
    const int* __restrict__ order, const float* __restrict__ gate,
    float* __restrict__ xh) {
  __shared__ float al[P_];
  int b = blockIdx.y;
  int e = blockIdx.x * 256 + threadIdx.x;
  for (int i = threadIdx.x; i < P_; i += 256) al[i] = alpha_ws[b * P_ + i];
  __syncthreads();
  int ob = order[b];
  const float* eb = enc + (long long)ob * P_ * E_ + e;
  float s = 0.f;
#pragma unroll 4
  for (int p = 0; p < P_; ++p) s += al[p] * eb[(long long)p * E_];
  xh[b * 2560 + e] = gate[b * 2048 + e] * s;
}

// ---------------------------------------------------------------------------
// LSTM elementwise
// ---------------------------------------------------------------------------
__global__ void lstm_ew_kernel(const float* __restrict__ g_emb,
                               const float* __restrict__ g_part,
                               float* __restrict__ c, float* __restrict__ h_next,
                               float* __restrict__ xh) {
  int idx = blockIdx.x * blockDim.x + threadIdx.x;
  int b = idx >> 9, d = idx & 511;
  int base = b * 2048 + d;
  float gi = g_emb[base], gf = g_emb[base + 512], gg = g_emb[base + 1024],
        go = g_emb[base + 1536];
#pragma unroll
  for (int z = 0; z < 5; ++z) {
    const float* gp = g_part + z * (128 * 2048) + base;
    gi += gp[0];
    gf += gp[512];
    gg += gp[1024];
    go += gp[1536];
  }
  float si = 1.f / (1.f + __expf(-gi));
  float sf = 1.f / (1.f + __expf(-gf));
  float so = 1.f / (1.f + __expf(-go));
  float cn = sf * c[idx] + si * tanhf(gg);
  float hn = so * tanhf(cn);
  c[idx] = cn;
  h_next[idx] = hn;
  xh[b * 2560 + 2048 + d] = hn;
}

// ---------------------------------------------------------------------------
// launch
// ---------------------------------------------------------------------------
extern "C" void kernel_launch(void* const* d_in, const int* in_sizes, int n_in,
                              void* d_out, int out_size, void* d_ws, size_t ws_size,
                              hipStream_t stream) {
  const float* enc       = (const float*)d_in[0];
  const int*   caps      = (const int*)d_in[1];
  const int*   lens      = (const int*)d_in[2];
  const float* emb       = (const float*)d_in[3];
  const float* enc_att_w = (const float*)d_in[4];
  const float* enc_att_b = (const float*)d_in[5];
  const float* dec_att_w = (const float*)d_in[6];
  const float* dec_att_b = (const float*)d_in[7];
  const float* full_att_w = (const float*)d_in[8];
  const float* full_att_b = (const float*)d_in[9];
  const float* init_h_w  = (const float*)d_in[10];
  const float* init_h_b  = (const float*)d_in[11];
  const float* init_c_w  = (const float*)d_in[12];
  const float* init_c_b  = (const float*)d_in[13];
  const float* f_beta_w  = (const float*)d_in[14];
  const float* f_beta_b  = (const float*)d_in[15];
  const float* lstm_w_ih = (const float*)d_in[16];
  const float* lstm_b_ih = (const float*)d_in[17];
  const float* lstm_w_hh = (const float*)d_in[18];
  const float* lstm_b_hh = (const float*)d_in[19];
  const float* fc_w      = (const float*)d_in[20];
  const float* fc_b      = (const float*)d_in[21];

  float* out = (float*)d_out;
  float* alphas_out = out + (long long)B_ * T_ * V_;

  // scratch in the (dead until the end) preds region of d_out
  float* g_all    = out;                       // 20*128*2048 = 5.24M floats
  float* g_part   = out + 6 * 1024 * 1024;     // 5*128*2048 = 1.31M floats
  float* encattwT = out + 8 * 1024 * 1024;     // 512*2048   = 1.05M floats

  // workspace layout
  float* ws = (float*)d_ws;
  float* att1  = ws;                                // 25088*512
  float* mean  = att1 + (long long)B_ * P_ * A_;    // 128*2048
  float* h_all = mean + B_ * E_;                    // 21*128*512
  float* c     = h_all + (T_ + 1) * B_ * D_;        // 128*512
  float* att2  = c + B_ * D_;                       // 128*512
  float* gate  = att2 + B_ * A_;                    // 128*2048
  float* xh    = gate + B_ * E_;                    // 128*2560
  float* alpha_ws = xh + B_ * (M_ + E_);            // 128*196
  int* order   = (int*)(alpha_ws + B_ * P_);
  int* declen  = order + B_;
  int* row_map = declen + B_;                       // 25088
  int* tok_rows = row_map + B_ * P_;                // 2560

  // 1. sort + index maps
  hipLaunchKernelGGL(order_kernel, dim3(1), dim3(256), 0, stream, lens, caps, order, declen,
                     row_map, tok_rows);
  // 2. mean
  hipLaunchKernelGGL(mean_kernel, dim3(E_ / 256, B_), dim3(256), 0, stream, enc, order, mean);
  // 3. transpose enc_att_w -> [512][2048]
  hipLaunchKernelGGL(transpose_kernel, dim3(16, 64), dim3(256), 0, stream, enc_att_w, encattwT);
  // 4/5. h0 (with xh-tail dup), c0 (fp32)
  hipLaunchKernelGGL(gemm32_kernel, dim3(D_ / 64, 2), dim3(256), 0, stream, mean, init_h_w,
                     init_h_b, h_all, B_, D_, E_, xh);
  hipLaunchKernelGGL(gemm32_kernel, dim3(D_ / 64, 2), dim3(256), 0, stream, mean, init_c_w,
                     init_c_b, c, B_, D_, E_, (float*)nullptr);
  // 6. att1 = enc_sorted @ enc_att_w + b   (plain bf16 MFMA)
  hipLaunchKernelGGL((mfma_gemm<0, false>), dim3(A_ / 128, (B_ * P_) / 128), dim3(256), 0,
                     stream, enc, E_, row_map, encattwT, E_, enc_att_b, (const float*)nullptr,
                     att1, A_, B_ * P_, A_, E_, (const float*)nullptr, (const int*)nullptr);
  // 7. g_all = emb(tok) @ W_ih[:, :512]^T + b_ih + b_hh   (split bf16 MFMA)
  hipLaunchKernelGGL((mfma_gemm<0, true>), dim3((4 * D_) / 128, (T_ * B_) / 128), dim3(256), 0,
                     stream, emb, M_, tok_rows, lstm_w_ih, M_ + E_, lstm_b_ih, lstm_b_hh,
                     g_all, 4 * D_, T_ * B_, 4 * D_, M_, (const float*)nullptr,
                     (const int*)nullptr);

  for (int t = 0; t < T_; ++t) {
    float* h_cur = h_all + (long long)t * B_ * D_;
    float* h_next = h_cur + B_ * D_;
    // att2 + gate (fused fp32)
    hipLaunchKernelGGL(step1_kernel, dim3(40, 2), dim3(256), 0, stream, h_cur, dec_att_w,
                       dec_att_b, f_beta_w, f_beta_b, att2, gate);
    // e + softmax + alpha
    hipLaunchKernelGGL(esm_kernel, dim3(B_), dim3(256), 0, stream, att1, att2, full_att_w,
                       full_att_b, declen, t, alpha_ws, alphas_out);
    // awe (writes gate*awe into xh head)
    hipLaunchKernelGGL(awe_kernel, dim3(E_ / 256, B_), dim3(256), 0, stream, alpha_ws, enc,
                       order, gate, xh);
    // split-K lstm GEMM partials (split bf16 MFMA)
    hipLaunchKernelGGL((mfma_gemm<2, true>), dim3((4 * D_) / 128, 1, 5), dim3(256), 0, stream,
                       xh, M_ + E_, (const int*)nullptr, lstm_w_ih, M_ + E_,
                       (const float*)nullptr, (const float*)nullptr, g_part, 4 * D_, B_,
                       4 * D_, D_, lstm_w_hh, (const int*)nullptr);
    // LSTM elementwise
    hipLaunchKernelGGL(lstm_ew_kernel, dim3((B_ * D_) / 256), dim3(256), 0, stream,
                       g_all + (long long)t * B_ * (4 * D_), g_part, c, h_next, xh);
  }

  // 8. batched fc over all (t,b), masked scatter (split bf16 MFMA)
  hipLaunchKernelGGL((mfma_gemm<1, true>), dim3((V_ + 127) / 128, (T_ * B_) / 128), dim3(256),
                     0, stream, h_all + B_ * D_, D_, (const int*)nullptr, fc_w, D_, fc_b,
                     (const float*)nullptr, out, V_, T_ * B_, V_, D_, (const float*)nullptr,
                     declen);
}